// Round 13
// baseline (75.561 us; speedup 1.0000x reference)
//
#include <hip/hip_runtime.h>

// Transposed conv (stride 2, 4x4, pad 2) as bf16 MFMA implicit GEMM, v10.
// x: (32,256,32,32) f32, W: (128,256,4,4) OIHW f32, b: (128,), out: (32,128,64,64) f32
// y[n,o,2a+pi,2b+pj] = bias[o] + sum_{c,du,dv} W[o,c,pi+2du,pj+2dv] * x[n,c,a+pi-1+du,b+pj-1+dv]
//
// v10: BARRIER-FREE main loop. Both W and x fragments are per-lane contiguous
// in the prepacked global layouts (L2-resident: 0.5 MB W + 2.4 MB x per XCD),
// so both load global->VGPR directly: per chunk = 8 coalesced b128 loads +
// 16 MFMA, two-slot ping-pong, NO LDS / NO barriers / NO waitcnt ledger in
// the loop. Rationale: v4/v5/v8/v9 (staged, barriered) all sit at 40-43us
// regardless of schedule -> the phase-lockstep staging structure is the cost.
// LDS is used only by the (proven) transpose epilogue.

typedef float  f32x4  __attribute__((ext_vector_type(4)));
typedef short  short8 __attribute__((ext_vector_type(8)));
typedef unsigned short ushort4v __attribute__((ext_vector_type(4)));
typedef unsigned short ushort8v __attribute__((ext_vector_type(8)));

__device__ __forceinline__ unsigned short f2bf(float f) {
    unsigned u = __builtin_bit_cast(unsigned, f);
    u += 0x7fffu + ((u >> 16) & 1u);          // RNE (inputs finite)
    return (unsigned short)(u >> 16);
}

// ---------------- layout constants (ushort units) ----------------
#define XP_U 288                 // per u' row: 36 v' * 8 c
#define XP_G 9792                // per (n,g): 34 * XP_U
#define XP_N 313344              // per n: 32 g * XP_G
#define WP_G 8192                // per (pi,g): 2 pj * 4 sub * 128 o * 8 c
#define WP_PI 262144             // 32 g * WP_G

// Wp2[pi][g][pj][sub][o][c8] = bf16(W[o][g*8+c8][pi+2du][pj+2dv]), sub=2du+dv
__global__ __launch_bounds__(256) void prepack_w2(const float* __restrict__ W,
                                                  unsigned short* __restrict__ wp) {
    int t = blockIdx.x * 256 + threadIdx.x;   // (o,c) in [0, 32768)
    int o = t >> 8, c = t & 255;
    int g = c >> 3, c8 = c & 7;
    const float4* src = (const float4*)(W + (size_t)(o * 256 + c) * 16);
    float4 q0 = src[0], q1 = src[1], q2 = src[2], q3 = src[3];
    float rows[4][4] = {{q0.x,q0.y,q0.z,q0.w},{q1.x,q1.y,q1.z,q1.w},
                        {q2.x,q2.y,q2.z,q2.w},{q3.x,q3.y,q3.z,q3.w}};
    #pragma unroll
    for (int pi = 0; pi < 2; ++pi)
    #pragma unroll
    for (int pj = 0; pj < 2; ++pj)
    #pragma unroll
    for (int du = 0; du < 2; ++du)
    #pragma unroll
    for (int dv = 0; dv < 2; ++dv)
        wp[pi*WP_PI + g*WP_G + pj*4096 + (du*2+dv)*1024 + o*8 + c8] =
            f2bf(rows[pi+2*du][pj+2*dv]);
}

// xp[n][g][u'][v'][c8] = bf16(x[n][g*8+c8][u'-1][v'-1]); u'/v' out of range -> 0.
__global__ __launch_bounds__(256) void prepack_x(const float* __restrict__ x,
                                                 unsigned short* __restrict__ xp) {
    __shared__ unsigned short xt[256 * 32];   // [c][v] bf16, 16 KB
    const int tid = threadIdx.x;
    const int up  = blockIdx.x;               // u' in [0,34)
    const int n   = blockIdx.y;
    const bool interior = (up >= 1 && up <= 32);

    if (interior) {
        const int u = up - 1;
        #pragma unroll
        for (int k = 0; k < 8; ++k) {
            int idx4 = tid + k * 256;          // [0,2048) float4 units
            int c = idx4 >> 3, v4 = idx4 & 7;
            float4 val = *(const float4*)(x + ((size_t)(n*256 + c)*32 + u)*32 + v4*4);
            ushort4v s = { f2bf(val.x), f2bf(val.y), f2bf(val.z), f2bf(val.w) };
            *(ushort4v*)&xt[c*32 + v4*4] = s;
        }
        __syncthreads();
    }

    #pragma unroll
    for (int s = 0; s < 5; ++s) {
        int id = tid + s * 256;                // (g, v') in [0, 32*36)
        if (id < 1152) {
            int g = id / 36, vp = id % 36;
            ushort8v o8 = {0,0,0,0,0,0,0,0};
            if (interior && vp >= 1 && vp <= 32) {      // v = vp-1 in [0,32)
                #pragma unroll
                for (int e = 0; e < 8; ++e)
                    o8[e] = xt[(g*8 + e)*32 + (vp - 1)];
            }
            *(ushort8v*)&xp[(size_t)n*XP_N + g*XP_G + up*XP_U + vp*8] = o8;
        }
    }
}

// Main: grid 1024 = (n, aq in [0,8), pi, oh), XCD-swizzled. 256 thr = 4 waves
// (pjw, half). Block tile: 64 o x (4 arows x 32 b x 2 pj). Wave: 64o x 64px.
// Barrier-free: per chunk 4 W b128 + 4 x b128 (global->VGPR) + 16 MFMA.
__global__ __launch_bounds__(256, 3) void tconv_main(
    const unsigned short* __restrict__ xp,
    const unsigned short* __restrict__ wp,
    const float* __restrict__ bias,
    float* __restrict__ out)
{
    __shared__ __align__(16) float epi[4224];   // epilogue transpose only, 16.9 KB

    const int tid  = threadIdx.x;
    const int lane = tid & 63;
    const int w    = tid >> 6;       // wave 0..3
    const int pjw  = w >> 1;
    const int half = w & 1;
    const int lg   = lane >> 4;      // sub = (du,dv)
    const int ln   = lane & 15;
    const int du   = lg >> 1, dv = lg & 1;

    const int bid = blockIdx.x;
    const int wg  = (bid & 7) * 128 + (bid >> 3);   // XCD swizzle (1024 % 8 == 0)
    const int n   = wg >> 5;
    const int rem = wg & 31;
    const int aq  = rem >> 2;
    const int pi  = (rem >> 1) & 1;
    const int oh  = rem & 1;
    const int a0  = aq * 4;

    // per-lane global bases (both fragment streams are lane-contiguous 16 B)
    const unsigned short* xpb = xp + (size_t)n * XP_N + (a0 + pi) * XP_U
                              + ((half * 2 + du) * XP_U + (ln + pjw + dv) * 8);
    const unsigned short* wpb = wp + pi * WP_PI + (pjw * 4 + lg) * 1024
                              + oh * 512 + ln * 8;

    f32x4 acc[4][4];
    #pragma unroll
    for (int i = 0; i < 4; ++i)
        #pragma unroll
        for (int jj = 0; jj < 4; ++jj)
            acc[i][jj] = (f32x4){0.f, 0.f, 0.f, 0.f};

    short8 wA[4], wB[4], xA[4], xB[4];

#define LOAD_W(CH, WS)                                                       \
    { const unsigned short* ws_ = wpb + (size_t)(CH) * WP_G;                 \
      WS[0] = *(const short8*)(ws_);                                         \
      WS[1] = *(const short8*)(ws_ + 128);                                   \
      WS[2] = *(const short8*)(ws_ + 256);                                   \
      WS[3] = *(const short8*)(ws_ + 384); }

#define LOAD_X(CH, XS)                                                       \
    { const unsigned short* xs_ = xpb + (size_t)(CH) * XP_G;                 \
      XS[0] = *(const short8*)(xs_);                                         \
      XS[1] = *(const short8*)(xs_ + 128);                                   \
      XS[2] = *(const short8*)(xs_ + XP_U);                                  \
      XS[3] = *(const short8*)(xs_ + XP_U + 128); }

#define MFMA16(WS, XS)                                                       \
    { _Pragma("unroll")                                                      \
      for (int i_ = 0; i_ < 4; ++i_)                                         \
          _Pragma("unroll")                                                  \
          for (int jj_ = 0; jj_ < 4; ++jj_)                                  \
              acc[i_][jj_] = __builtin_amdgcn_mfma_f32_16x16x32_bf16(        \
                  WS[i_], XS[jj_], acc[i_][jj_], 0, 0, 0); }

    LOAD_W(0, wA); LOAD_X(0, xA);
    LOAD_W(1, wB); LOAD_X(1, xB);

    for (int ch = 0; ch < 30; ch += 2) {
        MFMA16(wA, xA);
        LOAD_W(ch + 2, wA); LOAD_X(ch + 2, xA);
        MFMA16(wB, xB);
        LOAD_W(ch + 3, wB); LOAD_X(ch + 3, xB);
    }
    MFMA16(wA, xA);        // chunk 30
    MFMA16(wB, xB);        // chunk 31

#undef MFMA16
#undef LOAD_X
#undef LOAD_W

    // Epilogue (proven remap): write rows (r*4+lg) -> lg-quarters at bank
    // offsets 0/8/16/24; float2-pair reads cover all 32 banks per instr.
    #pragma unroll
    for (int i = 0; i < 4; ++i) {
        __syncthreads();
        f32x4 bv = *(const f32x4*)&bias[oh * 64 + i * 16 + lg * 4];
        #pragma unroll
        for (int jj = 0; jj < 4; ++jj) {
            int ar = half * 2 + (jj >> 1);
            int b  = (jj & 1) * 16 + ln;
            #pragma unroll
            for (int r = 0; r < 4; ++r)
                epi[((r * 4 + lg) * 8 + ar * 2 + pjw) * 33 + b] = acc[i][jj][r] + bv[r];
        }
        __syncthreads();
        #pragma unroll
        for (int k = 0; k < 4; ++k) {
            int f    = tid + k * 256;    // [0,1024) float4-store ids
            int row  = f >> 4;           // o_l'(row>>2) x ar(row&3)
            int q    = f & 15;
            float2 A = *(const float2*)&epi[(row * 2 + 0) * 33 + q * 2];
            float2 B = *(const float2*)&epi[(row * 2 + 1) * 33 + q * 2];
            float4 v = { A.x, B.x, A.y, B.y };
            int olp   = row >> 2;        // o_l' = r*4 + lg
            int o     = oh * 64 + i * 16 + ((olp & 3) << 2) + (olp >> 2);
            int i_out = 2 * (a0 + (row & 3)) + pi;
            *(float4*)&out[(((size_t)n * 128 + o) * 64 + i_out) * 64 + q * 4] = v;
        }
    }
}

// =================== fallback: round-2 kernel (proven) ===================
__global__ __launch_bounds__(256) void prepack_w(const float* __restrict__ W,
                                                 unsigned short* __restrict__ Wp) {
    int t = blockIdx.x * 256 + threadIdx.x;
    int o = t >> 8, c = t & 255;
    const float4* src = (const float4*)(W + (size_t)(o * 256 + c) * 16);
    float4 q0 = src[0], q1 = src[1], q2 = src[2], q3 = src[3];
    float rows[4][4] = {{q0.x,q0.y,q0.z,q0.w},{q1.x,q1.y,q1.z,q1.w},
                        {q2.x,q2.y,q2.z,q2.w},{q3.x,q3.y,q3.z,q3.w}};
    #pragma unroll
    for (int pi = 0; pi < 2; ++pi)
    #pragma unroll
    for (int pj = 0; pj < 2; ++pj)
    #pragma unroll
    for (int du = 0; du < 2; ++du)
    #pragma unroll
    for (int dv = 0; dv < 2; ++dv)
        Wp[((((pi*2+pj)*4 + du*2+dv)*128 + o)*256) + c] = f2bf(rows[pi+2*du][pj+2*dv]);
}

template<bool PRE>
__global__ __launch_bounds__(512, 2) void tconv_mfma(
    const float* __restrict__ x, const float* __restrict__ W,
    const unsigned short* __restrict__ Wp, const float* __restrict__ bias,
    float* __restrict__ out)
{
    __shared__ __align__(16) unsigned short xsh[2][9 * 34 * 8];
    __shared__ __align__(16) unsigned short wsh[2][2 * 4 * 128 * 8];

    const int tid = threadIdx.x;
    const int bid = blockIdx.x;
    const int pi  = bid & 1;
    const int aq  = (bid >> 1) & 3;
    const int n   = bid >> 3;
    const int a0  = aq * 8;
    const int u0  = a0 + pi - 1;

    const int l   = tid & 63;
    const int w   = tid >> 6;
    const int pjw = w >> 2;
    const int q   = w & 3;
    const int lg  = l >> 4;
    const int ln  = l & 15;

    const int sv = tid & 31;
    const int sg = tid >> 5;

    f32x4 acc[8][4];
    #pragma unroll
    for (int i = 0; i < 8; ++i)
        #pragma unroll
        for (int jj = 0; jj < 4; ++jj)
            acc[i][jj] = (f32x4){0.f, 0.f, 0.f, 0.f};

    float    xv[5];
    ushort4v wv[4];
    float4   wa[2], wb[2];

    auto stage_load = [&](int ch) {
        const int c0 = ch * 8;
        #pragma unroll
        for (int s = 0; s < 5; ++s) {
            int p = sg * 5 + s;
            if (p < 72) {
                int c = p & 7, rr = p >> 3;
                int u = u0 + rr;
                xv[s] = ((unsigned)u < 32u)
                      ? x[((n*256 + c0 + c)*32 + u)*32 + sv] : 0.f;
            }
        }
        if (PRE) {
            #pragma unroll
            for (int k = 0; k < 4; ++k) {
                int uu = tid + k * 512;
                int chalf = uu & 1, o = (uu >> 1) & 127;
                int sub = (uu >> 8) & 3, pjq = (uu >> 10) & 1;
                wv[k] = *(const ushort4v*)&Wp[(((pi*2 + pjq)*4 + sub)*128 + o)*256
                                              + c0 + chalf*4];
            }
        } else {
            #pragma unroll
            for (int k = 0; k < 2; ++k) {
                int pr = tid + k * 512;
                int o = pr >> 3, c = pr & 7;
                const float* base = W + ((o*256 + c0 + c) << 4) + pi*4;
                wa[k] = *(const float4*)base;
                wb[k] = *(const float4*)(base + 8);
            }
        }
    };

    auto stage_write = [&](int buf) {
        #pragma unroll
        for (int s = 0; s < 5; ++s) {
            int p = sg * 5 + s;
            if (p < 72) {
                int c = p & 7, rr = p >> 3;
                xsh[buf][(rr*34 + sv + 1)*8 + c] = f2bf(xv[s]);
            }
        }
        if (tid < 144) {
            int pr = tid >> 1;
            int rr = pr >> 3, c = pr & 7;
            int cw = (tid & 1) * 33;
            xsh[buf][(rr*34 + cw)*8 + c] = 0;
        }
        if (PRE) {
            #pragma unroll
            for (int k = 0; k < 4; ++k) {
                int uu = tid + k * 512;
                int chalf = uu & 1, o = (uu >> 1) & 127;
                int sub = (uu >> 8) & 3, pjq = (uu >> 10) & 1;
                *(ushort4v*)&wsh[buf][(((pjq*4 + sub)*128 + o)*8) + chalf*4] = wv[k];
            }
        } else {
            #pragma unroll
            for (int k = 0; k < 2; ++k) {
                int pr = tid + k * 512;
                int o = pr >> 3, c = pr & 7;
                float ra[4] = {wa[k].x, wa[k].y, wa[k].z, wa[k].w};
                float rb[4] = {wb[k].x, wb[k].y, wb[k].z, wb[k].w};
                #pragma unroll
                for (int pj2 = 0; pj2 < 2; ++pj2)
                #pragma unroll
                for (int duu = 0; duu < 2; ++duu)
                #pragma unroll
                for (int dvv = 0; dvv < 2; ++dvv) {
                    float val = duu ? rb[pj2 + 2*dvv] : ra[pj2 + 2*dvv];
                    wsh[buf][(((pj2*4 + duu*2 + dvv)*128 + o)*8) + c] = f2bf(val);
                }
            }
        }
    };

    stage_load(0);
    stage_write(0);
    __syncthreads();

    for (int ch = 0; ch < 32; ++ch) {
        const int cur = ch & 1;
        if (ch + 1 < 32) stage_load(ch + 1);

        short8 bfr[4];
        #pragma unroll
        for (int jj = 0; jj < 4; ++jj) {
            int arow = q*2 + (jj >> 1);
            int b    = (jj & 1)*16 + ln;
            int rr   = arow + (lg >> 1);
            int cw   = b + pjw + (lg & 1);
            bfr[jj]  = *(const short8*)&xsh[cur][(rr*34 + cw)*8];
        }
        #pragma unroll
        for (int i = 0; i < 8; ++i) {
            short8 av = *(const short8*)&wsh[cur][((pjw*4 + lg)*128 + i*16 + ln)*8];
            #pragma unroll
            for (int jj = 0; jj < 4; ++jj)
                acc[i][jj] = __builtin_amdgcn_mfma_f32_16x16x32_bf16(
                                 av, bfr[jj], acc[i][jj], 0, 0, 0);
        }

        if (ch + 1 < 32) stage_write(cur ^ 1);
        __syncthreads();
    }

    #pragma unroll
    for (int i = 0; i < 8; ++i) {
        const f32x4 bv = *(const f32x4*)&bias[i*16 + lg*4];
        #pragma unroll
        for (int jj = 0; jj < 4; ++jj) {
            int arow  = q*2 + (jj >> 1);
            int b     = (jj & 1)*16 + ln;
            int i_out = 2*(a0 + arow) + pi;
            int j_out = 2*b + pjw;
            int o0    = i*16 + lg*4;
            int base  = ((n*128 + o0)*64 + i_out)*64 + j_out;
            #pragma unroll
            for (int r = 0; r < 4; ++r)
                out[base + r*4096] = acc[i][jj][r] + bv[r];
        }
    }
}

extern "C" void kernel_launch(void* const* d_in, const int* in_sizes, int n_in,
                              void* d_out, int out_size, void* d_ws, size_t ws_size,
                              hipStream_t stream) {
    const float* x    = (const float*)d_in[0];
    const float* W    = (const float*)d_in[1];
    const float* bias = (const float*)d_in[2];
    float* out        = (float*)d_out;

    const size_t wp2_bytes = (size_t)2 * WP_PI * 2;          // 1 MB
    const size_t xp_bytes  = (size_t)32 * XP_N * 2;          // ~20 MB
    if (ws_size >= wp2_bytes + xp_bytes) {
        unsigned short* wp2 = (unsigned short*)d_ws;
        unsigned short* xpp = (unsigned short*)((char*)d_ws + wp2_bytes);
        prepack_w2<<<128, 256, 0, stream>>>(W, wp2);
        prepack_x<<<dim3(34, 32), 256, 0, stream>>>(x, xpp);
        tconv_main<<<1024, 256, 0, stream>>>(xpp, wp2, bias, out);
    } else if (ws_size >= (size_t)4*4*128*256*2) {
        unsigned short* Wp = (unsigned short*)d_ws;
        prepack_w<<<128, 256, 0, stream>>>(W, Wp);
        tconv_mfma<true><<<256, 512, 0, stream>>>(x, W, Wp, bias, out);
    } else {
        tconv_mfma<false><<<256, 512, 0, stream>>>(x, W, nullptr, bias, out);
    }
}

// Round 14
// 56.289 us; speedup vs baseline: 1.3424x; 1.3424x over previous
//
#include <hip/hip_runtime.h>

// Transposed conv (stride 2, 4x4, pad 2) as bf16 MFMA implicit GEMM, v11.
// x: (32,256,32,32) f32, W: (128,256,4,4) OIHW f32, b: (128,), out: (32,128,64,64) f32
// y[n,o,2a+pi,2b+pj] = bias[o] + sum_{c,du,dv} W[o,c,pi+2du,pj+2dv] * x[n,c,a+pi-1+du,b+pj-1+dv]
//
// v11 = v9 + SPLIT-K=2: 8-wave blocks (512 thr); K-group kg = w>>2 processes
// chunks [kg*16, kg*16+16) over the same 64o x 256px tile; partials reduced
// through LDS in the epilogue. Serial depth 16 -> 8 phases (the measured
// ~4000 cyc/phase fixed overhead amortizes over 2x the MFMA work). Same
// proven vmcnt(8) ledger; W LDS rows padded 512->528 sh (quarters at bank
// offsets 8/16/24 -> conflict-free b128 reads). Prepacks fused into one launch.

typedef float  f32x4  __attribute__((ext_vector_type(4)));
typedef short  short8 __attribute__((ext_vector_type(8)));
typedef unsigned short ushort4v __attribute__((ext_vector_type(4)));
typedef unsigned short ushort8v __attribute__((ext_vector_type(8)));

__device__ __forceinline__ unsigned short f2bf(float f) {
    unsigned u = __builtin_bit_cast(unsigned, f);
    u += 0x7fffu + ((u >> 16) & 1u);          // RNE (inputs finite)
    return (unsigned short)(u >> 16);
}

__device__ __forceinline__ void ld_lds16(const unsigned short* g, unsigned short* l) {
    __builtin_amdgcn_global_load_lds(
        (const __attribute__((address_space(1))) unsigned int*)g,
        (__attribute__((address_space(3))) unsigned int*)l,
        16, 0, 0);
}

// ---------------- layout constants (ushort units) ----------------
#define XP_U 288                 // per u' row: 36 v' * 8 c
#define XP_G 9792                // per (n,g): 34 * XP_U
#define XP_N 313344              // per n: 32 g * XP_G
#define WP_G 8192                // per (pi,g): 2 pj * 4 sub * 128 o * 8 c
#define WP_PI 262144             // 32 g * WP_G
#define WROW 528                 // LDS sh-stride per (pj,sub) 64o-row (512+16 pad)
#define WCH  4224                // 8 * WROW per chunk
#define WGRP 8448                // 2 chunks per group-buffer
#define WBUF 16896               // 2 groups per phase-buffer

// ---------- fused prepack: grid (38, 32), 256 thr ----------
// blocks up<34: prepack_x(up, n);  up>=34: prepack_w2 id = (up-34)*32 + n.
__global__ __launch_bounds__(256) void prepack_all(
    const float* __restrict__ x, const float* __restrict__ W,
    unsigned short* __restrict__ wp, unsigned short* __restrict__ xpp)
{
    const int tid = threadIdx.x;
    if (blockIdx.x >= 34) {
        int wid = (blockIdx.x - 34) * 32 + blockIdx.y;   // [0,128)
        int t = wid * 256 + tid;                          // (o,c)
        int o = t >> 8, c = t & 255;
        int g = c >> 3, c8 = c & 7;
        const float4* src = (const float4*)(W + (size_t)(o * 256 + c) * 16);
        float4 q0 = src[0], q1 = src[1], q2 = src[2], q3 = src[3];
        float rows[4][4] = {{q0.x,q0.y,q0.z,q0.w},{q1.x,q1.y,q1.z,q1.w},
                            {q2.x,q2.y,q2.z,q2.w},{q3.x,q3.y,q3.z,q3.w}};
        #pragma unroll
        for (int pi = 0; pi < 2; ++pi)
        #pragma unroll
        for (int pj = 0; pj < 2; ++pj)
        #pragma unroll
        for (int du = 0; du < 2; ++du)
        #pragma unroll
        for (int dv = 0; dv < 2; ++dv)
            wp[pi*WP_PI + g*WP_G + pj*4096 + (du*2+dv)*1024 + o*8 + c8] =
                f2bf(rows[pi+2*du][pj+2*dv]);
        return;
    }

    __shared__ unsigned short xt[256 * 32];   // [c][v] bf16, 16 KB
    const int up = blockIdx.x;                // u' in [0,34)
    const int n  = blockIdx.y;
    const bool interior = (up >= 1 && up <= 32);

    if (interior) {
        const int u = up - 1;
        #pragma unroll
        for (int k = 0; k < 8; ++k) {
            int idx4 = tid + k * 256;
            int c = idx4 >> 3, v4 = idx4 & 7;
            float4 val = *(const float4*)(x + ((size_t)(n*256 + c)*32 + u)*32 + v4*4);
            ushort4v s = { f2bf(val.x), f2bf(val.y), f2bf(val.z), f2bf(val.w) };
            *(ushort4v*)&xt[c*32 + v4*4] = s;
        }
        __syncthreads();
    }

    #pragma unroll
    for (int s = 0; s < 5; ++s) {
        int id = tid + s * 256;                // (g, v')
        if (id < 1152) {
            int g = id / 36, vp = id % 36;
            ushort8v o8 = {0,0,0,0,0,0,0,0};
            if (interior && vp >= 1 && vp <= 32) {      // v = vp-1 in [0,32)
                #pragma unroll
                for (int e = 0; e < 8; ++e)
                    o8[e] = xt[(g*8 + e)*32 + (vp - 1)];
            }
            *(ushort8v*)&xpp[(size_t)n*XP_N + g*XP_G + up*XP_U + vp*8] = o8;
        }
    }
}

// Main: grid 1024 = (n, aq in [0,8), pi, oh), XCD-swizzled. 512 thr = 8 waves:
// kg = w>>2 (K-group), sw = w&3 -> pjw = sw>>1, half = sw&1.
// Block tile: 64 o x (4 arows x 32 b x 2 pj); wave: 64o x 64px, 16 chunks.
__global__ __launch_bounds__(512, 4) void tconv_main(
    const unsigned short* __restrict__ xp,
    const unsigned short* __restrict__ wp,
    const float* __restrict__ bias,
    float* __restrict__ out)
{
    // W: [buf2][grp2][chunk2][8 rows][528] = 33792 sh = 67584 B (2 blocks/CU).
    // Epilogue epi (16.9 KB) + partial (20 KB) overlay.
    __shared__ __align__(16) unsigned short lds[33792];

    const int tid  = threadIdx.x;
    const int lane = tid & 63;
    const int w    = tid >> 6;       // wave 0..7
    const int kg   = w >> 2;         // K-group
    const int sw   = w & 3;
    const int pjw  = sw >> 1;
    const int half = sw & 1;
    const int lg   = lane >> 4;      // sub = (du,dv)
    const int ln   = lane & 15;
    const int du   = lg >> 1, dv = lg & 1;

    const int bid = blockIdx.x;
    const int wg  = (bid & 7) * 128 + (bid >> 3);   // XCD swizzle (1024 % 8 == 0)
    const int n   = wg >> 5;
    const int rem = wg & 31;
    const int aq  = rem >> 2;
    const int pi  = (rem >> 1) & 1;
    const int oh  = rem & 1;
    const int a0  = aq * 4;

    // group-relative bases (chunk ch = kg*16 + rel)
    const unsigned short* xpb = xp + (size_t)n * XP_N + (a0 + pi) * XP_U
                              + ((half * 2 + du) * XP_U + (ln + pjw + dv) * 8)
                              + (size_t)(kg * 16) * XP_G;
    const unsigned short* wpb = wp + pi * WP_PI + oh * 512
                              + (size_t)(kg * 16) * WP_G;

    f32x4 acc[4][4];
    #pragma unroll
    for (int i = 0; i < 4; ++i)
        #pragma unroll
        for (int jj = 0; jj < 4; ++jj)
            acc[i][jj] = (f32x4){0.f, 0.f, 0.f, 0.f};

    short8 xA[4], xB[4];

// Stage this group's phase-P W (rel chunks 2P, 2P+1) into buffer BUF: 4 DMA/wave.
// slot = cc*8 + pj*4 + sub; wave sw covers slots [sw*4, sw*4+4).
#define STAGE_W(P, BUF)                                                      \
    { _Pragma("unroll")                                                      \
      for (int s_ = 0; s_ < 4; ++s_) {                                       \
          int slot_ = sw * 4 + s_;                                           \
          int cc_   = slot_ >> 3;                                            \
          int pjs_  = slot_ & 7;                                             \
          const unsigned short* src_ = wpb + (size_t)(2*(P) + cc_) * WP_G    \
                  + (pjs_ >> 2) * 4096 + (pjs_ & 3) * 1024 + lane * 8;       \
          unsigned short* dst_ = lds + (BUF) * WBUF + kg * WGRP              \
                  + cc_ * WCH + pjs_ * WROW + lane * 8;                      \
          ld_lds16(src_, dst_); } }

// x fragment for group-relative chunk CH -> XS.
#define LOAD_X(CH, XS)                                                       \
    { const unsigned short* xs_ = xpb + (size_t)(CH) * XP_G;                 \
      XS[0] = *(const short8*)(xs_);                                         \
      XS[1] = *(const short8*)(xs_ + 128);                                   \
      XS[2] = *(const short8*)(xs_ + XP_U);                                  \
      XS[3] = *(const short8*)(xs_ + XP_U + 128); }

// 16 MFMA for chunk-slot CC of buffer BUF against XS (T5 setprio).
#define MFMA_CHUNK(BUF, CC, XS)                                              \
    { const unsigned short* wb_ = lds + (BUF) * WBUF + kg * WGRP             \
                                  + (CC) * WCH + (pjw * 4 + lg) * WROW + ln * 8; \
      __builtin_amdgcn_s_setprio(1);                                         \
      _Pragma("unroll")                                                      \
      for (int i_ = 0; i_ < 4; ++i_) {                                       \
          short8 av_ = *(const short8*)&wb_[i_ * 128];                       \
          _Pragma("unroll")                                                  \
          for (int jj_ = 0; jj_ < 4; ++jj_)                                  \
              acc[i_][jj_] = __builtin_amdgcn_mfma_f32_16x16x32_bf16(        \
                  av_, XS[jj_], acc[i_][jj_], 0, 0, 0);                      \
      }                                                                      \
      __builtin_amdgcn_s_setprio(0); }

// Phase header: retire own W(p) (8 newer x-ops in flight), barrier.
#define PHASE_HDR()                                                          \
    __builtin_amdgcn_sched_barrier(0);                                       \
    asm volatile("s_waitcnt vmcnt(8)" ::: "memory");                         \
    __builtin_amdgcn_s_barrier();                                            \
    __builtin_amdgcn_sched_barrier(0);

// Full phase p (p < 7): ledger entry 12 = [W(p):4, x(2p):4, x(2p+1):4].
#define PHASE_FULL(CUR, P)                                                   \
    {                                                                        \
        PHASE_HDR();                                                         \
        STAGE_W((P) + 1, (CUR) ^ 1);                                         \
        __builtin_amdgcn_sched_barrier(0);                                   \
        MFMA_CHUNK(CUR, 0, xA);                                              \
        LOAD_X(2 * (P) + 2, xA);                                             \
        MFMA_CHUNK(CUR, 1, xB);                                              \
        LOAD_X(2 * (P) + 3, xB);                                             \
    }

    // Prologue ledger: [W(0):4, x(0):4, x(1):4] = 12 outstanding.
    STAGE_W(0, 0);
    __builtin_amdgcn_sched_barrier(0);
    LOAD_X(0, xA);
    LOAD_X(1, xB);

    for (int pp = 0; pp < 6; pp += 2) {
        PHASE_FULL(0, pp);
        PHASE_FULL(1, pp + 1);
    }
    PHASE_FULL(0, 6);
    // Tail phase 7: entry = [W(7):4, x(14):4, x(15):4]; no new issues.
    PHASE_HDR();
    MFMA_CHUNK(1, 0, xA);
    MFMA_CHUNK(1, 1, xB);

#undef PHASE_FULL
#undef PHASE_HDR
#undef MFMA_CHUNK
#undef LOAD_X
#undef STAGE_W

    // ---- Epilogue: split-K reduce via LDS + transpose + coalesced stores ----
    // part[(sw*64+lane)*20 + jj*4 + r]: stride 20 dwords (16B-aligned, banks spread).
    float* epi  = (float*)lds;            // 4224 f32
    float* part = (float*)lds + 4224;     // 5120 f32
    const int pidx = (sw * 64 + lane) * 20;
    #pragma unroll
    for (int i = 0; i < 4; ++i) {
        __syncthreads();
        if (kg == 1) {
            #pragma unroll
            for (int jj = 0; jj < 4; ++jj)
                *(f32x4*)&part[pidx + jj * 4] = acc[i][jj];
        }
        __syncthreads();
        if (kg == 0) {
            f32x4 bv = *(const f32x4*)&bias[oh * 64 + i * 16 + lg * 4];
            #pragma unroll
            for (int jj = 0; jj < 4; ++jj) {
                int ar = half * 2 + (jj >> 1);
                int b  = (jj & 1) * 16 + ln;
                f32x4 pv = *(const f32x4*)&part[pidx + jj * 4];
                #pragma unroll
                for (int r = 0; r < 4; ++r)
                    epi[((r * 4 + lg) * 8 + ar * 2 + pjw) * 33 + b] =
                        acc[i][jj][r] + pv[r] + bv[r];
            }
        }
        __syncthreads();
        #pragma unroll
        for (int k = 0; k < 2; ++k) {
            int f    = tid + k * 512;    // [0,1024) float4-store ids
            int row  = f >> 4;           // o_l'(row>>2) x ar(row&3)
            int q    = f & 15;
            float2 A = *(const float2*)&epi[(row * 2 + 0) * 33 + q * 2];
            float2 B = *(const float2*)&epi[(row * 2 + 1) * 33 + q * 2];
            float4 v = { A.x, B.x, A.y, B.y };
            int olp   = row >> 2;        // o_l' = r*4 + lg
            int o     = oh * 64 + i * 16 + ((olp & 3) << 2) + (olp >> 2);
            int i_out = 2 * (a0 + (row & 3)) + pi;
            *(float4*)&out[(((size_t)n * 128 + o) * 64 + i_out) * 64 + q * 4] = v;
        }
    }
}

// =================== fallback: round-2 kernel (proven) ===================
__global__ __launch_bounds__(256) void prepack_w(const float* __restrict__ W,
                                                 unsigned short* __restrict__ Wp) {
    int t = blockIdx.x * 256 + threadIdx.x;
    int o = t >> 8, c = t & 255;
    const float4* src = (const float4*)(W + (size_t)(o * 256 + c) * 16);
    float4 q0 = src[0], q1 = src[1], q2 = src[2], q3 = src[3];
    float rows[4][4] = {{q0.x,q0.y,q0.z,q0.w},{q1.x,q1.y,q1.z,q1.w},
                        {q2.x,q2.y,q2.z,q2.w},{q3.x,q3.y,q3.z,q3.w}};
    #pragma unroll
    for (int pi = 0; pi < 2; ++pi)
    #pragma unroll
    for (int pj = 0; pj < 2; ++pj)
    #pragma unroll
    for (int du = 0; du < 2; ++du)
    #pragma unroll
    for (int dv = 0; dv < 2; ++dv)
        Wp[((((pi*2+pj)*4 + du*2+dv)*128 + o)*256) + c] = f2bf(rows[pi+2*du][pj+2*dv]);
}

template<bool PRE>
__global__ __launch_bounds__(512, 2) void tconv_mfma(
    const float* __restrict__ x, const float* __restrict__ W,
    const unsigned short* __restrict__ Wp, const float* __restrict__ bias,
    float* __restrict__ out)
{
    __shared__ __align__(16) unsigned short xsh[2][9 * 34 * 8];
    __shared__ __align__(16) unsigned short wsh[2][2 * 4 * 128 * 8];

    const int tid = threadIdx.x;
    const int bid = blockIdx.x;
    const int pi  = bid & 1;
    const int aq  = (bid >> 1) & 3;
    const int n   = bid >> 3;
    const int a0  = aq * 8;
    const int u0  = a0 + pi - 1;

    const int l   = tid & 63;
    const int w   = tid >> 6;
    const int pjw = w >> 2;
    const int q   = w & 3;
    const int lg  = l >> 4;
    const int ln  = l & 15;

    const int sv = tid & 31;
    const int sg = tid >> 5;

    f32x4 acc[8][4];
    #pragma unroll
    for (int i = 0; i < 8; ++i)
        #pragma unroll
        for (int jj = 0; jj < 4; ++jj)
            acc[i][jj] = (f32x4){0.f, 0.f, 0.f, 0.f};

    float    xv[5];
    ushort4v wv[4];
    float4   wa[2], wb[2];

    auto stage_load = [&](int ch) {
        const int c0 = ch * 8;
        #pragma unroll
        for (int s = 0; s < 5; ++s) {
            int p = sg * 5 + s;
            if (p < 72) {
                int c = p & 7, rr = p >> 3;
                int u = u0 + rr;
                xv[s] = ((unsigned)u < 32u)
                      ? x[((n*256 + c0 + c)*32 + u)*32 + sv] : 0.f;
            }
        }
        if (PRE) {
            #pragma unroll
            for (int k = 0; k < 4; ++k) {
                int uu = tid + k * 512;
                int chalf = uu & 1, o = (uu >> 1) & 127;
                int sub = (uu >> 8) & 3, pjq = (uu >> 10) & 1;
                wv[k] = *(const ushort4v*)&Wp[(((pi*2 + pjq)*4 + sub)*128 + o)*256
                                              + c0 + chalf*4];
            }
        } else {
            #pragma unroll
            for (int k = 0; k < 2; ++k) {
                int pr = tid + k * 512;
                int o = pr >> 3, c = pr & 7;
                const float* base = W + ((o*256 + c0 + c) << 4) + pi*4;
                wa[k] = *(const float4*)base;
                wb[k] = *(const float4*)(base + 8);
            }
        }
    };

    auto stage_write = [&](int buf) {
        #pragma unroll
        for (int s = 0; s < 5; ++s) {
            int p = sg * 5 + s;
            if (p < 72) {
                int c = p & 7, rr = p >> 3;
                xsh[buf][(rr*34 + sv + 1)*8 + c] = f2bf(xv[s]);
            }
        }
        if (tid < 144) {
            int pr = tid >> 1;
            int rr = pr >> 3, c = pr & 7;
            int cw = (tid & 1) * 33;
            xsh[buf][(rr*34 + cw)*8 + c] = 0;
        }
        if (PRE) {
            #pragma unroll
            for (int k = 0; k < 4; ++k) {
                int uu = tid + k * 512;
                int chalf = uu & 1, o = (uu >> 1) & 127;
                int sub = (uu >> 8) & 3, pjq = (uu >> 10) & 1;
                *(ushort4v*)&wsh[buf][(((pjq*4 + sub)*128 + o)*8) + chalf*4] = wv[k];
            }
        } else {
            #pragma unroll
            for (int k = 0; k < 2; ++k) {
                int pr = tid + k * 512;
                int o = pr >> 3, c = pr & 7;
                float ra[4] = {wa[k].x, wa[k].y, wa[k].z, wa[k].w};
                float rb[4] = {wb[k].x, wb[k].y, wb[k].z, wb[k].w};
                #pragma unroll
                for (int pj2 = 0; pj2 < 2; ++pj2)
                #pragma unroll
                for (int duu = 0; duu < 2; ++duu)
                #pragma unroll
                for (int dvv = 0; dvv < 2; ++dvv) {
                    float val = duu ? rb[pj2 + 2*dvv] : ra[pj2 + 2*dvv];
                    wsh[buf][(((pj2*4 + duu*2 + dvv)*128 + o)*8) + c] = f2bf(val);
                }
            }
        }
    };

    stage_load(0);
    stage_write(0);
    __syncthreads();

    for (int ch = 0; ch < 32; ++ch) {
        const int cur = ch & 1;
        if (ch + 1 < 32) stage_load(ch + 1);

        short8 bfr[4];
        #pragma unroll
        for (int jj = 0; jj < 4; ++jj) {
            int arow = q*2 + (jj >> 1);
            int b    = (jj & 1)*16 + ln;
            int rr   = arow + (lg >> 1);
            int cw   = b + pjw + (lg & 1);
            bfr[jj]  = *(const short8*)&xsh[cur][(rr*34 + cw)*8];
        }
        #pragma unroll
        for (int i = 0; i < 8; ++i) {
            short8 av = *(const short8*)&wsh[cur][((pjw*4 + lg)*128 + i*16 + ln)*8];
            #pragma unroll
            for (int jj = 0; jj < 4; ++jj)
                acc[i][jj] = __builtin_amdgcn_mfma_f32_16x16x32_bf16(
                                 av, bfr[jj], acc[i][jj], 0, 0, 0);
        }

        if (ch + 1 < 32) stage_write(cur ^ 1);
        __syncthreads();
    }

    #pragma unroll
    for (int i = 0; i < 8; ++i) {
        const f32x4 bv = *(const f32x4*)&bias[i*16 + lg*4];
        #pragma unroll
        for (int jj = 0; jj < 4; ++jj) {
            int arow  = q*2 + (jj >> 1);
            int b     = (jj & 1)*16 + ln;
            int i_out = 2*(a0 + arow) + pi;
            int j_out = 2*b + pjw;
            int o0    = i*16 + lg*4;
            int base  = ((n*128 + o0)*64 + i_out)*64 + j_out;
            #pragma unroll
            for (int r = 0; r < 4; ++r)
                out[base + r*4096] = acc[i][jj][r] + bv[r];
        }
    }
}

extern "C" void kernel_launch(void* const* d_in, const int* in_sizes, int n_in,
                              void* d_out, int out_size, void* d_ws, size_t ws_size,
                              hipStream_t stream) {
    const float* x    = (const float*)d_in[0];
    const float* W    = (const float*)d_in[1];
    const float* bias = (const float*)d_in[2];
    float* out        = (float*)d_out;

    const size_t wp2_bytes = (size_t)2 * WP_PI * 2;          // 1 MB
    const size_t xp_bytes  = (size_t)32 * XP_N * 2;          // ~20 MB
    if (ws_size >= wp2_bytes + xp_bytes) {
        unsigned short* wp2 = (unsigned short*)d_ws;
        unsigned short* xpp = (unsigned short*)((char*)d_ws + wp2_bytes);
        prepack_all<<<dim3(38, 32), 256, 0, stream>>>(x, W, wp2, xpp);
        tconv_main<<<1024, 512, 0, stream>>>(xpp, wp2, bias, out);
    } else if (ws_size >= (size_t)4*4*128*256*2) {
        unsigned short* Wp = (unsigned short*)d_ws;
        prepack_w<<<128, 256, 0, stream>>>(W, Wp);
        tconv_mfma<true><<<256, 512, 0, stream>>>(x, W, Wp, bias, out);
    } else {
        tconv_mfma<false><<<256, 512, 0, stream>>>(x, W, nullptr, bias, out);
    }
}